// Round 4
// baseline (990.173 us; speedup 1.0000x reference)
//
#include <hip/hip_runtime.h>
#include <cstdint>

#define TOK   8192
#define DIM   1024
#define NE    8
#define HID   4096
#define CAP   8320
#define HROWS 17408

typedef __attribute__((ext_vector_type(4))) float f32x4;
typedef __attribute__((ext_vector_type(8))) short s16x8;

__device__ inline unsigned short f2bf(float f) {
  union { float f; unsigned u; } v; v.f = f;
  unsigned r = v.u + 0x7FFFu + ((v.u >> 16) & 1u);
  return (unsigned short)(r >> 16);
}
__device__ inline float bf2f(unsigned short u) {
  union { unsigned u; float f; } v; v.u = ((unsigned)u) << 16;
  return v.f;
}

// async global->LDS, 16B per lane. LDS dest is wave-uniform base + lane*16.
__device__ __forceinline__ void gload_lds16(const void* gptr, void* lptr) {
  __builtin_amdgcn_global_load_lds(
      (const __attribute__((address_space(1))) unsigned*)gptr,
      (__attribute__((address_space(3))) unsigned*)lptr, 16, 0, 0);
}

// ---------------- fused transpose+cast for W1 and W2 (one launch) ----------------
// W [E][K][N] fp32 -> Wt [E][N][K] bf16. id<8192: W1 (K=1024,N=4096); else W2 (K=4096,N=1024).
__global__ __launch_bounds__(256) void transpose_both_kernel(const float* __restrict__ W1,
                                                             unsigned short* __restrict__ w1t,
                                                             const float* __restrict__ W2,
                                                             unsigned short* __restrict__ w2t) {
  int id = blockIdx.x;
  const float* W; unsigned short* Wt; int K, N, n0, k0, e;
  if (id < 8192) {
    e = id >> 10; int r = id & 1023;
    K = DIM; N = HID; n0 = (r & 63) * 64; k0 = (r >> 6) * 64;
    W = W1; Wt = w1t;
  } else {
    id -= 8192;
    e = id >> 10; int r = id & 1023;
    K = HID; N = DIM; n0 = (r & 15) * 64; k0 = (r >> 4) * 64;
    W = W2; Wt = w2t;
  }
  const float* We = W + (size_t)e * K * N;
  unsigned short* Wte = Wt + (size_t)e * K * N;
  __shared__ float tile[64][65];
  int tid = threadIdx.x;
  int c4 = (tid & 15) * 4;
  int r8 = tid >> 4;
#pragma unroll
  for (int rr = 0; rr < 64; rr += 16) {
    f32x4 v = *(const f32x4*)(We + (size_t)(k0 + r8 + rr) * N + n0 + c4);
    tile[r8 + rr][c4 + 0] = v[0];
    tile[r8 + rr][c4 + 1] = v[1];
    tile[r8 + rr][c4 + 2] = v[2];
    tile[r8 + rr][c4 + 3] = v[3];
  }
  __syncthreads();
#pragma unroll
  for (int rr = 0; rr < 64; rr += 16) {
    int n = r8 + rr;
    ushort4 o;
    o.x = f2bf(tile[c4 + 0][n]);
    o.y = f2bf(tile[c4 + 1][n]);
    o.z = f2bf(tile[c4 + 2][n]);
    o.w = f2bf(tile[c4 + 3][n]);
    *(ushort4*)(Wte + (size_t)(n0 + n) * K + k0 + c4) = o;
  }
}

// ---------------- router (fp32 exact) + fused x->bf16 cast ----------------
__global__ __launch_bounds__(256) void router_kernel(const float* __restrict__ x,
                                                     const float* __restrict__ noise,
                                                     const float* __restrict__ Wg,
                                                     const float* __restrict__ bg,
                                                     const float* __restrict__ Wn,
                                                     const float* __restrict__ bn,
                                                     int* __restrict__ cnt,
                                                     int* __restrict__ tokL,
                                                     float* __restrict__ gateL,
                                                     int* __restrict__ tokmap,
                                                     unsigned short* __restrict__ xb) {
  int t = blockIdx.x * 4 + (threadIdx.x >> 6);
  int lane = threadIdx.x & 63;
  float ag[8] = {0, 0, 0, 0, 0, 0, 0, 0};
  float an[8] = {0, 0, 0, 0, 0, 0, 0, 0};
  const float* xr = x + (size_t)t * DIM;
#pragma unroll
  for (int it = 0; it < 4; it++) {
    int d0 = it * 256 + lane * 4;
    f32x4 xv = *(const f32x4*)(xr + d0);
    ushort4 o;
    o.x = f2bf(xv[0]); o.y = f2bf(xv[1]); o.z = f2bf(xv[2]); o.w = f2bf(xv[3]);
    *(ushort4*)(xb + (size_t)t * DIM + d0) = o;
#pragma unroll
    for (int j = 0; j < 4; j++) {
      int d = d0 + j;
      float xs = xv[j];
      f32x4 g0 = *(const f32x4*)(Wg + d * 8);
      f32x4 g1 = *(const f32x4*)(Wg + d * 8 + 4);
      f32x4 n0 = *(const f32x4*)(Wn + d * 8);
      f32x4 n1 = *(const f32x4*)(Wn + d * 8 + 4);
      ag[0] += xs * g0[0]; ag[1] += xs * g0[1]; ag[2] += xs * g0[2]; ag[3] += xs * g0[3];
      ag[4] += xs * g1[0]; ag[5] += xs * g1[1]; ag[6] += xs * g1[2]; ag[7] += xs * g1[3];
      an[0] += xs * n0[0]; an[1] += xs * n0[1]; an[2] += xs * n0[2]; an[3] += xs * n0[3];
      an[4] += xs * n1[0]; an[5] += xs * n1[1]; an[6] += xs * n1[2]; an[7] += xs * n1[3];
    }
  }
#pragma unroll
  for (int off = 32; off >= 1; off >>= 1) {
#pragma unroll
    for (int e = 0; e < 8; e++) {
      ag[e] += __shfl_xor(ag[e], off);
      an[e] += __shfl_xor(an[e], off);
    }
  }
  if (lane == 0) {
    float v[8];
#pragma unroll
    for (int e = 0; e < 8; e++) {
      float lg = ag[e] + bg[e];
      float ln = an[e] + bn[e];
      float sp = (ln > 20.f) ? ln : log1pf(expf(ln));  // stable softplus
      v[e] = lg + noise[(size_t)t * 8 + e] * sp;
    }
    int i1 = 0; float m1 = v[0];
#pragma unroll
    for (int e = 1; e < 8; e++) { if (v[e] > m1) { m1 = v[e]; i1 = e; } }
    int i2 = -1; float m2 = -1e30f;
#pragma unroll
    for (int e = 0; e < 8; e++) { if (e != i1 && v[e] > m2) { m2 = v[e]; i2 = e; } }
    float e2 = expf(m2 - m1);
    float denom = 1.f + e2;
    float g1 = 1.f / denom;
    float g2 = e2 / denom;
    int p1 = atomicAdd(&cnt[i1], 1);
    tokL[i1 * CAP + p1] = t; gateL[i1 * CAP + p1] = g1;
    int p2 = atomicAdd(&cnt[i2], 1);
    tokL[i2 * CAP + p2] = t; gateL[i2 * CAP + p2] = g2;
    tokmap[t * 2 + 0] = (i1 << 20) | p1;
    tokmap[t * 2 + 1] = (i2 << 20) | p2;
  }
}

// ---------------- pad lists to 128-multiples; prefix-sum h offsets ----------------
__global__ __launch_bounds__(256) void pad_kernel(const int* __restrict__ cnt,
                                                  int* __restrict__ hoff,
                                                  int* __restrict__ tokL,
                                                  float* __restrict__ gateL) {
  __shared__ int cp_s[8];
  if (threadIdx.x == 0) {
    int off = 0;
    for (int e = 0; e < 8; e++) {
      int c = cnt[e];
      int cp = (c + 127) & ~127;
      cp_s[e] = cp;
      hoff[e] = off;
      off += cp;
    }
  }
  __syncthreads();
  for (int e = 0; e < 8; e++) {
    int c = cnt[e], cp = cp_s[e];
    for (int i = c + threadIdx.x; i < cp; i += 256) {
      tokL[e * CAP + i] = 0;
      gateL[e * CAP + i] = 0.f;
    }
  }
}

// ---------------- GEMM1: h = relu(gather(x) @ W1[e] + b1[e]) ----------------
// 128x128 tile, BK=64, XOR-swizzled LDS (conflict-free fragment reads).
__global__ __launch_bounds__(256) void gemm1_kernel(const unsigned short* __restrict__ xb,
                                                    const unsigned short* __restrict__ w1t,
                                                    const float* __restrict__ b1,
                                                    const int* __restrict__ tokL,
                                                    const int* __restrict__ cnt,
                                                    const int* __restrict__ hoff,
                                                    unsigned short* __restrict__ h) {
  const int e = blockIdx.z;
  const int c = cnt[e];
  const int cp = (c + 127) & ~127;
  const int rb = blockIdx.y;
  if (rb * 128 >= cp) return;
  const int nb = blockIdx.x;
  const int row0 = hoff[e] + rb * 128;

  __shared__ unsigned short As[128 * 64];  // unpadded (global_load_lds); k-seg XOR-swizzled
  __shared__ unsigned short Bs[128 * 64];
  __shared__ int toks[128];

  const int tid = threadIdx.x;
  if (tid < 128) toks[tid] = tokL[e * CAP + rb * 128 + tid];
  __syncthreads();

  const int lane = tid & 63;
  const int w = tid >> 6;
  const int lr = lane >> 3;     // 0..7: row within 8-row staging group
  const int lseg = lane & 7;    // 0..7: physical k-segment (8 bf16 each)
  // LDS slot (row r, phys seg p) holds global k-seg (p ^ (r&7)); here r&7 == lr.
  const int gseg = (lseg ^ lr) * 8;

  int tokA[4];
#pragma unroll
  for (int t = 0; t < 4; t++) tokA[t] = toks[w * 32 + t * 8 + lr];
  const unsigned short* pA[4];
  const unsigned short* pB[4];
  const unsigned short* bbase = w1t + (size_t)e * HID * DIM + gseg;
#pragma unroll
  for (int t = 0; t < 4; t++) {
    pA[t] = xb + (size_t)tokA[t] * DIM + gseg;
    pB[t] = bbase + (size_t)(nb * 128 + w * 32 + t * 8 + lr) * DIM;
  }

  const int wm = (w >> 1) * 64;
  const int wn = (w & 1) * 64;
  const int fr = lane & 15;
  const int fq = lane >> 4;
  const int p0 = (fq ^ (fr & 7)) * 8;  // physical seg offset (shorts) for k-step 0

  f32x4 acc[4][4];
#pragma unroll
  for (int i = 0; i < 4; i++)
#pragma unroll
    for (int j = 0; j < 4; j++) acc[i][j] = (f32x4){0.f, 0.f, 0.f, 0.f};

  for (int k0 = 0; k0 < DIM; k0 += 64) {
    __syncthreads();
#pragma unroll
    for (int t = 0; t < 4; t++) {
      gload_lds16(pA[t] + k0, As + (w * 32 + t * 8) * 64);
      gload_lds16(pB[t] + k0, Bs + (w * 32 + t * 8) * 64);
    }
    __syncthreads();
#pragma unroll
    for (int s = 0; s < 2; s++) {
      const int ks = p0 ^ (s * 32);
      s16x8 af[4], bf[4];
#pragma unroll
      for (int i = 0; i < 4; i++) af[i] = *(const s16x8*)(As + (wm + i * 16 + fr) * 64 + ks);
#pragma unroll
      for (int j = 0; j < 4; j++) bf[j] = *(const s16x8*)(Bs + (wn + j * 16 + fr) * 64 + ks);
#pragma unroll
      for (int i = 0; i < 4; i++)
#pragma unroll
        for (int j = 0; j < 4; j++)
          acc[i][j] = __builtin_amdgcn_mfma_f32_16x16x32_bf16(af[i], bf[j], acc[i][j], 0, 0, 0);
    }
  }

  const float* b1p = b1 + (size_t)e * HID + nb * 128 + wn;
#pragma unroll
  for (int j = 0; j < 4; j++) {
    float bias = b1p[j * 16 + fr];
#pragma unroll
    for (int i = 0; i < 4; i++)
#pragma unroll
      for (int v = 0; v < 4; v++) {
        float val = acc[i][j][v] + bias;
        val = fmaxf(val, 0.f);
        int m = wm + i * 16 + fq * 4 + v;
        h[(size_t)(row0 + m) * HID + nb * 128 + wn + j * 16 + fr] = f2bf(val);
      }
  }
}

// ---------------- GEMM2: ybuf[row] = h[row] @ W2[e] + b2[e] ----------------
// 128x64 tile (2080 active blocks -> small tail), BK=64, XOR-swizzled LDS.
__global__ __launch_bounds__(256) void gemm2_kernel(const unsigned short* __restrict__ h,
                                                    const unsigned short* __restrict__ w2t,
                                                    const float* __restrict__ b2,
                                                    const int* __restrict__ cnt,
                                                    const int* __restrict__ hoff,
                                                    unsigned short* __restrict__ ybuf) {
  const int e = blockIdx.z;
  const int c = cnt[e];
  const int cp = (c + 127) & ~127;
  const int rb = blockIdx.y;
  if (rb * 128 >= cp) return;
  const int nb = blockIdx.x;  // 0..15, 64-wide N tile
  const int row0 = hoff[e] + rb * 128;

  __shared__ unsigned short As[128 * 64];
  __shared__ unsigned short Bs[64 * 64];

  const int tid = threadIdx.x;
  const int lane = tid & 63;
  const int w = tid >> 6;
  const int lr = lane >> 3;
  const int lseg = lane & 7;
  const int gseg = (lseg ^ lr) * 8;

  const unsigned short* pA[4];
#pragma unroll
  for (int t = 0; t < 4; t++)
    pA[t] = h + (size_t)(row0 + w * 32 + t * 8 + lr) * HID + gseg;
  const unsigned short* pB[2];
  const unsigned short* bbase = w2t + (size_t)e * DIM * HID + gseg;
#pragma unroll
  for (int t = 0; t < 2; t++)
    pB[t] = bbase + (size_t)(nb * 64 + w * 16 + t * 8 + lr) * HID;

  const int wm = (w >> 1) * 64;
  const int wn = (w & 1) * 32;
  const int fr = lane & 15;
  const int fq = lane >> 4;
  const int p0 = (fq ^ (fr & 7)) * 8;

  f32x4 acc[4][2];
#pragma unroll
  for (int i = 0; i < 4; i++)
#pragma unroll
    for (int j = 0; j < 2; j++) acc[i][j] = (f32x4){0.f, 0.f, 0.f, 0.f};

  for (int k0 = 0; k0 < HID; k0 += 64) {
    __syncthreads();
#pragma unroll
    for (int t = 0; t < 4; t++)
      gload_lds16(pA[t] + k0, As + (w * 32 + t * 8) * 64);
#pragma unroll
    for (int t = 0; t < 2; t++)
      gload_lds16(pB[t] + k0, Bs + (w * 16 + t * 8) * 64);
    __syncthreads();
#pragma unroll
    for (int s = 0; s < 2; s++) {
      const int ks = p0 ^ (s * 32);
      s16x8 af[4], bf[2];
#pragma unroll
      for (int i = 0; i < 4; i++) af[i] = *(const s16x8*)(As + (wm + i * 16 + fr) * 64 + ks);
#pragma unroll
      for (int j = 0; j < 2; j++) bf[j] = *(const s16x8*)(Bs + (wn + j * 16 + fr) * 64 + ks);
#pragma unroll
      for (int i = 0; i < 4; i++)
#pragma unroll
        for (int j = 0; j < 2; j++)
          acc[i][j] = __builtin_amdgcn_mfma_f32_16x16x32_bf16(af[i], bf[j], acc[i][j], 0, 0, 0);
    }
  }

  const float* b2p = b2 + (size_t)e * DIM + nb * 64 + wn;
#pragma unroll
  for (int j = 0; j < 2; j++) {
    float bias = b2p[j * 16 + fr];
#pragma unroll
    for (int i = 0; i < 4; i++)
#pragma unroll
      for (int v = 0; v < 4; v++) {
        int m = wm + i * 16 + fq * 4 + v;
        ybuf[(size_t)(row0 + m) * DIM + nb * 64 + wn + j * 16 + fr] =
            f2bf(acc[i][j][v] + bias);
      }
  }
}

// ---------------- combine: out[t] = g1*ybuf[row1] + g2*ybuf[row2] ----------------
__global__ __launch_bounds__(256) void combine_kernel(const unsigned short* __restrict__ ybuf,
                                                      const int* __restrict__ tokmap,
                                                      const float* __restrict__ gateL,
                                                      const int* __restrict__ hoff,
                                                      float* __restrict__ out) {
  const int t = blockIdx.x;
  const int m1 = tokmap[t * 2 + 0];
  const int m2 = tokmap[t * 2 + 1];
  const int e1 = m1 >> 20, p1 = m1 & 0xFFFFF;
  const int e2 = m2 >> 20, p2 = m2 & 0xFFFFF;
  const float g1 = gateL[e1 * CAP + p1];
  const float g2 = gateL[e2 * CAP + p2];
  const size_t r1 = (size_t)(hoff[e1] + p1) * DIM;
  const size_t r2 = (size_t)(hoff[e2] + p2) * DIM;
  const int d = threadIdx.x * 4;
  ushort4 u1 = *(const ushort4*)(ybuf + r1 + d);
  ushort4 u2 = *(const ushort4*)(ybuf + r2 + d);
  f32x4 o;
  o[0] = g1 * bf2f(u1.x) + g2 * bf2f(u2.x);
  o[1] = g1 * bf2f(u1.y) + g2 * bf2f(u2.y);
  o[2] = g1 * bf2f(u1.z) + g2 * bf2f(u2.z);
  o[3] = g1 * bf2f(u1.w) + g2 * bf2f(u2.w);
  *(f32x4*)(out + (size_t)t * DIM + d) = o;
}

extern "C" void kernel_launch(void* const* d_in, const int* in_sizes, int n_in,
                              void* d_out, int out_size, void* d_ws, size_t ws_size,
                              hipStream_t stream) {
  const float* x     = (const float*)d_in[0];
  const float* noise = (const float*)d_in[1];
  const float* Wg    = (const float*)d_in[2];
  const float* bg    = (const float*)d_in[3];
  const float* Wn    = (const float*)d_in[4];
  const float* bn    = (const float*)d_in[5];
  const float* W1    = (const float*)d_in[6];
  const float* b1    = (const float*)d_in[7];
  const float* W2    = (const float*)d_in[8];
  const float* b2    = (const float*)d_in[9];
  float* out = (float*)d_out;

  char* ws = (char*)d_ws;
  int*            cnt    = (int*)(ws + 0);
  int*            hoff   = (int*)(ws + 32);
  int*            tokL   = (int*)(ws + 256);
  float*          gateL  = (float*)(ws + 266496);
  unsigned short* xb     = (unsigned short*)(ws + 532736);
  unsigned short* w1t    = (unsigned short*)(ws + 17309952);   // dead after gemm1
  unsigned short* w2t    = (unsigned short*)(ws + 84418816);
  unsigned short* hbuf   = (unsigned short*)(ws + 151527680);
  int*            tokmap = (int*)(ws + 294134016);
  unsigned short* ybuf   = w1t;  // reuse (gemm1 finished reading w1t before gemm2 writes)
  // total ws need: ~294.2 MB

  hipMemsetAsync(cnt, 0, 64, stream);

  transpose_both_kernel<<<16384, 256, 0, stream>>>(W1, w1t, W2, w2t);
  router_kernel<<<TOK / 4, 256, 0, stream>>>(x, noise, Wg, bg, Wn, bn, cnt, tokL, gateL, tokmap, xb);
  pad_kernel<<<1, 256, 0, stream>>>(cnt, hoff, tokL, gateL);
  gemm1_kernel<<<dim3(HID / 128, 24, NE), 256, 0, stream>>>(xb, w1t, b1, tokL, cnt, hoff, hbuf);
  gemm2_kernel<<<dim3(DIM / 64, 24, NE), 256, 0, stream>>>(hbuf, w2t, b2, cnt, hoff, ybuf);
  combine_kernel<<<TOK, 256, 0, stream>>>(ybuf, tokmap, gateL, hoff, out);
}